// Round 9
// baseline (375.220 us; speedup 1.0000x reference)
//
#include <hip/hip_runtime.h>
#include <hip/hip_bf16.h>
#include <stdint.h>

// Problem: B=8, S=2048, F=1024 single-head causal self-attention.
// R4: P'=exp(s-16) folded into scores epilogue. R5-R7: 8-phase abandoned.
// R10/R12: pad compaction, input-side (xc gather; kc/vTc from compacted rows,
//   plain epilogues) -> 335us. k_qkv=120 (573 TF); scores+pv ~190 for 40 GFLOP
//   (208 TF) -- 2.8x slower per block on the IDENTICAL tile fn; cause unknown
//   because top-5 counters only ever show the single slowest kernel.
// R13: (a) split k_qkv -> k_q + k_kv so each is ~60us and the slowest of
//   scores/pv becomes visible in top-5 next round (measurement). (b) k_kv uses
//   a 256x128 tile (512thr, 8 waves 4Mx2N, 24KB LDS): barriers/FLOP halved,
//   staged bytes/FLOP x0.73 -- a within-round A/B vs k_q's 128^2 on the same
//   GEMM shape. kc tail rows (>=cnt) may be NaN-garbage: discarded via the
//   sIdx sentinel mask in scores (proven R10/R12). vTc epilogue zero-fills all
//   columns pv reads.

#define S_LEN 2048
#define F_DIM 1024
#define NBATCH 8
#define BS_TOT (NBATCH * S_LEN)   // 16384 rows

typedef __attribute__((ext_vector_type(8))) short bf16x8;
typedef __attribute__((ext_vector_type(4))) float f32x4;
typedef unsigned short u16;

__device__ __forceinline__ u16 f32_to_bf16_rne(float f) {
    union { float f; uint32_t u; } v; v.f = f;
    uint32_t u = v.u;
    u += 0x7FFFu + ((u >> 16) & 1u);
    return (u16)(u >> 16);
}
__device__ __forceinline__ float bf16_to_f32(u16 h) {
    union { uint32_t u; float f; } v; v.u = ((uint32_t)h) << 16;
    return v.f;
}

// async global->LDS, 16B per lane per instruction (global_load_lds_dwordx4)
__device__ __forceinline__ void gload_lds16(const u16* g, u16* l) {
    __builtin_amdgcn_global_load_lds(
        (const __attribute__((address_space(1))) void*)g,
        (__attribute__((address_space(3))) void*)l,
        16, 0, 0);
}

// ---------------- fp32 -> bf16 converts ----------------
__global__ __launch_bounds__(256) void cvt_f32_bf16(const float* __restrict__ in,
                                                    u16* __restrict__ out, int n) {
    int i = (blockIdx.x * 256 + threadIdx.x) * 4;
    if (i + 3 < n) {
        float4 f = *(const float4*)(in + i);
        ushort4 o;
        o.x = f32_to_bf16_rne(f.x); o.y = f32_to_bf16_rne(f.y);
        o.z = f32_to_bf16_rne(f.z); o.w = f32_to_bf16_rne(f.w);
        *(ushort4*)(out + i) = o;
    }
}

__global__ __launch_bounds__(256) void cvt_w3(const float* __restrict__ Wq,
                                              const float* __restrict__ Wk,
                                              const float* __restrict__ Wv,
                                              u16* __restrict__ Wb) {
    const int which = blockIdx.y;
    const float* in = (which == 0) ? Wq : (which == 1) ? Wk : Wv;
    int i = (blockIdx.x * 256 + threadIdx.x) * 4;
    float4 f = *(const float4*)(in + i);
    ushort4 o;
    o.x = f32_to_bf16_rne(f.x); o.y = f32_to_bf16_rne(f.y);
    o.z = f32_to_bf16_rne(f.z); o.w = f32_to_bf16_rne(f.w);
    *(ushort4*)(Wb + (size_t)which * F_DIM * F_DIM + i) = o;
}

// ---------------- pad prefix scan (one block per batch) ----------------
// sIdx[b][c]  = original s for compacted c; sentinel S_LEN for c >= cnt
// kneed[b][it] = # valid keys with s <= (it+1)*128-1   (kneed[b][15] = cnt)
__global__ __launch_bounds__(256) void k_scan(const int* __restrict__ pad,
                                              int* __restrict__ sIdx,
                                              int* __restrict__ kneed) {
    const int b = blockIdx.x;
    const int tid = threadIdx.x;
    const int* p = pad + b * S_LEN;
    __shared__ int part[256];
    __shared__ int cnt_s;
    int v[8]; int sum = 0; const int s0 = tid * 8;
#pragma unroll
    for (int i = 0; i < 8; i++) { v[i] = p[s0 + i]; sum += v[i]; }
    part[tid] = sum;
    __syncthreads();
    if (tid == 0) {
        int acc = 0;
        for (int i = 0; i < 256; i++) { int t = part[i]; part[i] = acc; acc += t; }
        cnt_s = acc;
    }
    __syncthreads();
    int run = part[tid];
#pragma unroll
    for (int i = 0; i < 8; i++) {
        const int s = s0 + i;
        if (v[i]) sIdx[b * S_LEN + run] = s;
        run += v[i];
    }
    const int cnt = cnt_s;
    for (int c = cnt + tid; c < S_LEN; c += 256) sIdx[b * S_LEN + c] = S_LEN;
    if (tid < 16) {
        const int et = (tid + 1) * 16 - 1;
        kneed[b * 16 + tid] = (et == 255) ? cnt : part[et + 1];
    }
}

// ---------------- gather valid rows: xc[b][c][:] = xb[b][sIdx[c]][:] -------------
__global__ __launch_bounds__(256) void k_gather(const u16* __restrict__ xb,
                                                const int* __restrict__ sIdx,
                                                const int* __restrict__ kneed,
                                                u16* __restrict__ xc) {
    const int b = blockIdx.x >> 11, c = blockIdx.x & 2047;
    if (c >= kneed[b * 16 + 15]) return;
    const int s = sIdx[b * S_LEN + c];
    const ushort4 v = *(const ushort4*)(xb + ((size_t)b * S_LEN + s) * F_DIM
                                        + threadIdx.x * 4);
    *(ushort4*)(xc + ((size_t)b * S_LEN + c) * F_DIM + threadIdx.x * 4) = v;
}

// ---------------- core 128x128 B^T GEMM tile (m97 structure) ----------------
// 256 threads = 4 waves in 2x2, each wave 64x64 via 4x4 mfma_f32_16x16x32_bf16.
// NOTE: __shared__ here is per-INSTANTIATION and summed across a kernel's calls.
template<class Epi>
__device__ __forceinline__ void gemm_tile_128(
    const u16* __restrict__ A, int lda,
    const u16* __restrict__ Bt, int ldb,
    int m0, int n0, int K, float alpha, Epi epi)
{
    __shared__ u16 la[128 * 32];
    __shared__ u16 lb[128 * 32];

    const int tid  = threadIdx.x;
    const int lane = tid & 63;
    const int wave = tid >> 6;
    const int wm = (wave & 1) * 64;
    const int wn = (wave >> 1) * 64;

    f32x4 acc[4][4];
#pragma unroll
    for (int mt = 0; mt < 4; mt++)
#pragma unroll
        for (int nt = 0; nt < 4; nt++)
            acc[mt][nt] = f32x4{0.f, 0.f, 0.f, 0.f};

    const int mrow = wm + (lane & 15);
    const int nrow = wn + (lane & 15);
    const int koff = (lane >> 4) * 8;

    const int cb0 = wave * 64;
    const int cb1 = wave * 64 + 256;
    const int lrow = lane >> 2;
    const int lcol = (lane & 3) * 8;
    const u16* pa0 = A  + (size_t)(m0 + (cb0 >> 2) + lrow) * lda + lcol;
    const u16* pa1 = A  + (size_t)(m0 + (cb1 >> 2) + lrow) * lda + lcol;
    const u16* pb0 = Bt + (size_t)(n0 + (cb0 >> 2) + lrow) * ldb + lcol;
    const u16* pb1 = Bt + (size_t)(n0 + (cb1 >> 2) + lrow) * ldb + lcol;
    u16* qa0 = la + cb0 * 8;
    u16* qa1 = la + cb1 * 8;
    u16* qb0 = lb + cb0 * 8;
    u16* qb1 = lb + cb1 * 8;

    for (int kk = 0; kk < K; kk += 32) {
        __syncthreads();
        gload_lds16(pa0 + kk, qa0);
        gload_lds16(pa1 + kk, qa1);
        gload_lds16(pb0 + kk, qb0);
        gload_lds16(pb1 + kk, qb1);
        __syncthreads();

        bf16x8 fa[4], fb[4];
#pragma unroll
        for (int t = 0; t < 4; t++) {
            fa[t] = *(const bf16x8*)(la + (mrow + t * 16) * 32 + koff);
            fb[t] = *(const bf16x8*)(lb + (nrow + t * 16) * 32 + koff);
        }
#pragma unroll
        for (int mt = 0; mt < 4; mt++)
#pragma unroll
            for (int nt = 0; nt < 4; nt++)
                acc[mt][nt] = __builtin_amdgcn_mfma_f32_16x16x32_bf16(
                    fa[mt], fb[nt], acc[mt][nt], 0, 0, 0);
    }

    // C/D layout col=lane&15, row=(lane>>4)*4+reg  [verified m89/m91]
    const int col   = lane & 15;
    const int rquad = (lane >> 4) * 4;
#pragma unroll
    for (int mt = 0; mt < 4; mt++)
#pragma unroll
        for (int nt = 0; nt < 4; nt++) {
            const int n = n0 + wn + nt * 16 + col;
#pragma unroll
            for (int r = 0; r < 4; r++) {
                const int m = m0 + wm + mt * 16 + rquad + r;
                epi(m, n, acc[mt][nt][r] * alpha);
            }
        }
}

// ---------------- 256x128 B^T GEMM tile (A/B candidate: bigger M) ----------------
// 512 threads = 8 waves in 4(M)x2(N), each wave 64x64 via 4x4 mfma. LDS 24KB.
// Staging per k-step: A 16KB in 2 gload rounds, B 8KB in 1 round; barriers/FLOP
// halved and B-staging amortized over 256 A-rows vs 128.
template<class Epi>
__device__ __forceinline__ void gemm_tile_256m(
    const u16* __restrict__ A, int lda,
    const u16* __restrict__ Bt, int ldb,
    int m0, int n0, int K, float alpha, Epi epi)
{
    __shared__ u16 la[256 * 32];
    __shared__ u16 lb[128 * 32];

    const int tid  = threadIdx.x;      // 0..511
    const int lane = tid & 63;
    const int wave = tid >> 6;         // 0..7
    const int wm = (wave & 3) * 64;    // 4 M-waves
    const int wn = (wave >> 2) * 64;   // 2 N-waves

    f32x4 acc[4][4];
#pragma unroll
    for (int mt = 0; mt < 4; mt++)
#pragma unroll
        for (int nt = 0; nt < 4; nt++)
            acc[mt][nt] = f32x4{0.f, 0.f, 0.f, 0.f};

    const int mrow = wm + (lane & 15);
    const int nrow = wn + (lane & 15);
    const int koff = (lane >> 4) * 8;

    // gload geometry: wave-uniform LDS base wvo + lane*16B; global row/granule:
    // row = wave*16 + lane/4, granule = lane&3.
    const int wvo  = wave * 512;               // u16 units (1 KiB per wave)
    const int lrow = wave * 16 + (lane >> 2);  // 0..127
    const int lcol = (lane & 3) * 8;
    const u16* pa0 = A  + (size_t)(m0 + lrow) * lda + lcol;
    const u16* pa1 = A  + (size_t)(m0 + 128 + lrow) * lda + lcol;
    const u16* pb0 = Bt + (size_t)(n0 + lrow) * ldb + lcol;

    for (int kk = 0; kk < K; kk += 32) {
        __syncthreads();
        gload_lds16(pa0 + kk, la + wvo);
        gload_lds16(pa1 + kk, la + 4096 + wvo);
        gload_lds16(pb0 + kk, lb + wvo);
        __syncthreads();

        bf16x8 fa[4], fb[4];
#pragma unroll
        for (int t = 0; t < 4; t++) {
            fa[t] = *(const bf16x8*)(la + (mrow + t * 16) * 32 + koff);
            fb[t] = *(const bf16x8*)(lb + (nrow + t * 16) * 32 + koff);
        }
#pragma unroll
        for (int mt = 0; mt < 4; mt++)
#pragma unroll
            for (int nt = 0; nt < 4; nt++)
                acc[mt][nt] = __builtin_amdgcn_mfma_f32_16x16x32_bf16(
                    fa[mt], fb[nt], acc[mt][nt], 0, 0, 0);
    }

    const int col   = lane & 15;
    const int rquad = (lane >> 4) * 4;
#pragma unroll
    for (int mt = 0; mt < 4; mt++)
#pragma unroll
        for (int nt = 0; nt < 4; nt++) {
            const int n = n0 + wn + nt * 16 + col;
#pragma unroll
            for (int r = 0; r < 4; r++) {
                const int m = m0 + wm + mt * 16 + rquad + r;
                epi(m, n, acc[mt][nt][r] * alpha);
            }
        }
}

// ---------------- Q projection (128^2 tile, full rows) ----------------
// XCD swizzle: xcd = bx&7 owns m-tiles [16*xcd,16*xcd+16).
__global__ __launch_bounds__(256) void k_q(const u16* __restrict__ xb,
                                           const u16* __restrict__ Wb,
                                           const float* __restrict__ bq,
                                           u16* __restrict__ q) {
    const int bx = blockIdx.x;
    const int xcd = bx & 7;
    const int idx = bx >> 3;
    const int m0 = (xcd * 16 + (idx >> 3)) * 128;
    const int n0 = (idx & 7) * 128;
    gemm_tile_128(xb, F_DIM, Wb, F_DIM, m0, n0, F_DIM, 1.0f,
        [&](int m, int n, float v) {
            q[(size_t)m * F_DIM + n] = f32_to_bf16_rne(v + bq[n]);
        });
}

// ---------------- K/V projection (256x128 tile, compacted rows) ----------------
// y=0 -> kc plain store; y=1 -> vTc[b][n][c] transposed, (c<cnt)?h:0 fills tail.
// grid x = t*8+b (b -> XCD); t: mtile=t>>3 (0..7, early-exit >= cnt), ntile=t&7.
__global__ __launch_bounds__(512) void k_kv(const u16* __restrict__ xc,
                                            const u16* __restrict__ Wb,
                                            const float* __restrict__ bk,
                                            const float* __restrict__ bv,
                                            const int* __restrict__ kneed,
                                            u16* __restrict__ kc,
                                            u16* __restrict__ vTc) {
    const int which = blockIdx.y;              // 0=k, 1=v (block-uniform)
    const int bx = blockIdx.x;
    const int b = bx & 7;
    const int t = bx >> 3;                     // 0..63
    const int m0 = (t >> 3) * 256;
    const int n0 = (t & 7) * 128;
    const int cnt = kneed[b * 16 + 15];
    if (m0 >= cnt) return;
    const float* bias = which ? bv : bk;
    const u16* W = Wb + (size_t)(which + 1) * F_DIM * F_DIM;
    const u16* A = xc + (size_t)b * S_LEN * F_DIM;
    gemm_tile_256m(A, F_DIM, W, F_DIM, m0, n0, F_DIM, 1.0f,
        [&](int m, int n, float v) {
            const u16 h = f32_to_bf16_rne(v + bias[n]);
            if (which == 0)
                kc[((size_t)b * S_LEN + m) * F_DIM + n] = h;
            else
                vTc[((size_t)b * F_DIM + n) * S_LEN + m] = (m < cnt) ? h : (u16)0;
        });
}

// ---------------- scores -> P'c = exp(s-16), compacted cols + fused row sums ------
// 1D grid 1088; batch = bx&7 -> XCD. Early-exit tiles beyond kneed(it).
// Mask via sIdx[c] <= m (sentinel covers pad+gap -> writes 0).
__global__ __launch_bounds__(256) void k_scores(const u16* __restrict__ q,
                                                const u16* __restrict__ kc,
                                                const int* __restrict__ sIdx,
                                                const int* __restrict__ kneed,
                                                u16* __restrict__ Pp,
                                                float* __restrict__ lsum) {
    const int b = blockIdx.x & 7;
    const int t = blockIdx.x >> 3;        // 0..135 triangular index
    int it = 0, base = 0;
    while (base + it + 1 <= t) { base += it + 1; it++; }
    const int jt = t - base;
    if (jt * 128 >= kneed[b * 16 + it]) return;
    const int* sIb = sIdx + b * S_LEN;
    u16* Pb = Pp + (size_t)b * S_LEN * S_LEN;

    float rs[16];
#pragma unroll
    for (int i = 0; i < 16; i++) rs[i] = 0.f;

    gemm_tile_128(q + (size_t)b * S_LEN * F_DIM, F_DIM,
                  kc + (size_t)b * S_LEN * F_DIM, F_DIM,
                  it * 128, jt * 128, F_DIM, 0.03125f,
        [&](int m, int n, float v) {
            u16 o = 0;
            if (sIb[n] <= m)
                o = f32_to_bf16_rne(__expf(v - 16.0f));
            Pb[(size_t)m * S_LEN + n] = o;
            const int i = m & 63;
            rs[((i >> 4) << 2) | (i & 3)] += bf16_to_f32(o);
        });

    const int lane  = threadIdx.x & 63;
    const int wave  = threadIdx.x >> 6;
    const int wm    = (wave & 1) * 64;
    const int rquad = (lane >> 4) * 4;
    float* lb = lsum + b * S_LEN + it * 128 + wm;
#pragma unroll
    for (int i = 0; i < 16; i++) {        // i = mt*4 + r
        float s = rs[i];
        s += __shfl_xor(s, 1);
        s += __shfl_xor(s, 2);
        s += __shfl_xor(s, 4);
        s += __shfl_xor(s, 8);            // uniform across the 16 col-lanes
        if ((lane & 15) == 0)
            atomicAdd(&lb[((i >> 2) << 4) + rquad + (i & 3)], s);
    }
}

// ---------------- PV: out = (P'c @ Vc) / l, Keff = ceil128(kneed(it)) ---------
// 1D grid 1024; batch = bx&7 -> XCD. Heavy/light interleave on it.
__global__ __launch_bounds__(256) void k_pv(const u16* __restrict__ Pp,
                                            const u16* __restrict__ vTc,
                                            const float* __restrict__ lsum,
                                            const int* __restrict__ kneed,
                                            float* __restrict__ out) {
    const int b = blockIdx.x & 7;
    const int rest = blockIdx.x >> 3;
    const int j = rest >> 3;
    const int nt = rest & 7;
    const int it = (j & 1) ? (j >> 1) : (15 - (j >> 1));
    const int Keff = (kneed[b * 16 + it] + 127) & ~127;
    const float* ls = lsum + b * S_LEN;
    float* ob = out + (size_t)b * S_LEN * F_DIM;

    const int lane  = threadIdx.x & 63;
    const int wave  = threadIdx.x >> 6;
    const int wm    = (wave & 1) * 64;
    const int rquad = (lane >> 4) * 4;
    const int mb    = it * 128 + wm;
    float myinv[16];
#pragma unroll
    for (int i = 0; i < 16; i++)          // i = mt*4 + r
        myinv[i] = 1.0f / ls[mb + ((i >> 2) << 4) + rquad + (i & 3)];

    gemm_tile_128(Pp + (size_t)b * S_LEN * S_LEN, S_LEN,
                  vTc + (size_t)b * F_DIM * S_LEN, S_LEN,
                  it * 128, nt * 128, Keff, 1.0f,
        [&](int m, int n, float v) {
            const int i = m & 63;
            ob[(size_t)m * F_DIM + n] = v * myinv[((i >> 4) << 2) | (i & 3)];
        });
}

extern "C" void kernel_launch(void* const* d_in, const int* in_sizes, int n_in,
                              void* d_out, int out_size, void* d_ws, size_t ws_size,
                              hipStream_t stream) {
    const float* x  = (const float*)d_in[0];
    // d_in[1] = attn_mask (causal tril) — structure hard-coded
    const int* pad  = (const int*)d_in[2];
    const float* Wq = (const float*)d_in[3];
    const float* bq = (const float*)d_in[4];
    const float* Wk = (const float*)d_in[5];
    const float* bk = (const float*)d_in[6];
    const float* Wv = (const float*)d_in[7];
    const float* bv = (const float*)d_in[8];
    float* out = (float*)d_out;

    char* ws = (char*)d_ws;
    // layout:
    //   [0,32M)    q    bf16 [8][2048][1024]
    //   [32,64M)   kc   bf16 [8][2048][1024]  (compacted rows; >=cnt garbage/masked)
    //   [64,96M)   vTc  bf16 [8][1024][2048]  (compacted cols; tail zeroed by epi)
    //   [96,160M)  P'c  bf16 [8][2048][2048]  -- first 32M double as xc before scores
    //   [160,192M) xb   bf16 [16384][1024]
    //   [192,198M) Wb   bf16 [3][1024][1024]
    //   [200M)     lsum f32 [16384]
    //   [202M)     sIdx i32 [8][2048]
    //   [203M)     kneed i32 [8][16]
    u16* q    = (u16*)(ws);
    u16* kc   = (u16*)(ws + 32ull * 1024 * 1024);
    u16* vTc  = (u16*)(ws + 64ull * 1024 * 1024);
    u16* Pp   = (u16*)(ws + 96ull * 1024 * 1024);
    u16* xc   = (u16*)(ws + 96ull * 1024 * 1024);   // aliases Pp[0:32M), dead by scores
    u16* xb   = (u16*)(ws + 160ull * 1024 * 1024);
    u16* Wb   = (u16*)(ws + 192ull * 1024 * 1024);
    float* il = (float*)(ws + 200ull * 1024 * 1024);
    int* sIdx = (int*)(ws + 202ull * 1024 * 1024);
    int* kneed= (int*)(ws + 203ull * 1024 * 1024);

    const int BSF = BS_TOT * F_DIM;      // 16,777,216
    const int FF = F_DIM * F_DIM;        // 1,048,576

    hipMemsetAsync(il, 0, BS_TOT * sizeof(float), stream);

    cvt_f32_bf16<<<BSF / 1024, 256, 0, stream>>>(x, xb, BSF);
    cvt_w3<<<dim3(FF / 1024, 3), 256, 0, stream>>>(Wq, Wk, Wv, Wb);
    k_scan<<<NBATCH, 256, 0, stream>>>(pad, sIdx, kneed);
    k_gather<<<BS_TOT, 256, 0, stream>>>(xb, sIdx, kneed, xc);

    k_q<<<1024, 256, 0, stream>>>(xb, Wb, bq, q);
    k_kv<<<dim3(512, 2), 512, 0, stream>>>(xc, Wb, bk, bv, kneed, kc, vTc);

    k_scores<<<1088, 256, 0, stream>>>(q, kc, sIdx, kneed, Pp, il);

    k_pv<<<1024, 256, 0, stream>>>(Pp, vTc, il, kneed, out);
}

// Round 10
// 349.276 us; speedup vs baseline: 1.0743x; 1.0743x over previous
//
#include <hip/hip_runtime.h>
#include <hip/hip_bf16.h>
#include <stdint.h>

// Problem: B=8, S=2048, F=1024 single-head causal self-attention.
// R4: P'=exp(s-16) folded into scores epilogue. R5-R7: 8-phase abandoned.
// R12: input-side pad compaction -> 335us (best).
// R13: 256x128 tile for k_kv FALSIFIED (103.8us vs ~60 expected; MfmaUtil 14.5%,
//   2 blocks/CU). Third confirmation (R9/R11/R13): this serial 2-barrier staging
//   structure needs small blocks + high co-residency (implicit m114 overlap);
//   tile-size variants are done.
// R14: revert k_kv to the 128^2 tile; KEEP the k_q/k_kv split so the slowest of
//   scores/pv (~95-110us by ledger) finally surfaces in top-5 with counters.
//   Pipeline is otherwise byte-equivalent to R12's 335us run.

#define S_LEN 2048
#define F_DIM 1024
#define NBATCH 8
#define BS_TOT (NBATCH * S_LEN)   // 16384 rows

typedef __attribute__((ext_vector_type(8))) short bf16x8;
typedef __attribute__((ext_vector_type(4))) float f32x4;
typedef unsigned short u16;

__device__ __forceinline__ u16 f32_to_bf16_rne(float f) {
    union { float f; uint32_t u; } v; v.f = f;
    uint32_t u = v.u;
    u += 0x7FFFu + ((u >> 16) & 1u);
    return (u16)(u >> 16);
}
__device__ __forceinline__ float bf16_to_f32(u16 h) {
    union { uint32_t u; float f; } v; v.u = ((uint32_t)h) << 16;
    return v.f;
}

// async global->LDS, 16B per lane per instruction (global_load_lds_dwordx4)
__device__ __forceinline__ void gload_lds16(const u16* g, u16* l) {
    __builtin_amdgcn_global_load_lds(
        (const __attribute__((address_space(1))) void*)g,
        (__attribute__((address_space(3))) void*)l,
        16, 0, 0);
}

// ---------------- fp32 -> bf16 converts ----------------
__global__ __launch_bounds__(256) void cvt_f32_bf16(const float* __restrict__ in,
                                                    u16* __restrict__ out, int n) {
    int i = (blockIdx.x * 256 + threadIdx.x) * 4;
    if (i + 3 < n) {
        float4 f = *(const float4*)(in + i);
        ushort4 o;
        o.x = f32_to_bf16_rne(f.x); o.y = f32_to_bf16_rne(f.y);
        o.z = f32_to_bf16_rne(f.z); o.w = f32_to_bf16_rne(f.w);
        *(ushort4*)(out + i) = o;
    }
}

__global__ __launch_bounds__(256) void cvt_w3(const float* __restrict__ Wq,
                                              const float* __restrict__ Wk,
                                              const float* __restrict__ Wv,
                                              u16* __restrict__ Wb) {
    const int which = blockIdx.y;
    const float* in = (which == 0) ? Wq : (which == 1) ? Wk : Wv;
    int i = (blockIdx.x * 256 + threadIdx.x) * 4;
    float4 f = *(const float4*)(in + i);
    ushort4 o;
    o.x = f32_to_bf16_rne(f.x); o.y = f32_to_bf16_rne(f.y);
    o.z = f32_to_bf16_rne(f.z); o.w = f32_to_bf16_rne(f.w);
    *(ushort4*)(Wb + (size_t)which * F_DIM * F_DIM + i) = o;
}

// ---------------- pad prefix scan (one block per batch) ----------------
// sIdx[b][c]  = original s for compacted c; sentinel S_LEN for c >= cnt
// kneed[b][it] = # valid keys with s <= (it+1)*128-1   (kneed[b][15] = cnt)
__global__ __launch_bounds__(256) void k_scan(const int* __restrict__ pad,
                                              int* __restrict__ sIdx,
                                              int* __restrict__ kneed) {
    const int b = blockIdx.x;
    const int tid = threadIdx.x;
    const int* p = pad + b * S_LEN;
    __shared__ int part[256];
    __shared__ int cnt_s;
    int v[8]; int sum = 0; const int s0 = tid * 8;
#pragma unroll
    for (int i = 0; i < 8; i++) { v[i] = p[s0 + i]; sum += v[i]; }
    part[tid] = sum;
    __syncthreads();
    if (tid == 0) {
        int acc = 0;
        for (int i = 0; i < 256; i++) { int t = part[i]; part[i] = acc; acc += t; }
        cnt_s = acc;
    }
    __syncthreads();
    int run = part[tid];
#pragma unroll
    for (int i = 0; i < 8; i++) {
        const int s = s0 + i;
        if (v[i]) sIdx[b * S_LEN + run] = s;
        run += v[i];
    }
    const int cnt = cnt_s;
    for (int c = cnt + tid; c < S_LEN; c += 256) sIdx[b * S_LEN + c] = S_LEN;
    if (tid < 16) {
        const int et = (tid + 1) * 16 - 1;
        kneed[b * 16 + tid] = (et == 255) ? cnt : part[et + 1];
    }
}

// ---------------- gather valid rows: xc[b][c][:] = xb[b][sIdx[c]][:] -------------
__global__ __launch_bounds__(256) void k_gather(const u16* __restrict__ xb,
                                                const int* __restrict__ sIdx,
                                                const int* __restrict__ kneed,
                                                u16* __restrict__ xc) {
    const int b = blockIdx.x >> 11, c = blockIdx.x & 2047;
    if (c >= kneed[b * 16 + 15]) return;
    const int s = sIdx[b * S_LEN + c];
    const ushort4 v = *(const ushort4*)(xb + ((size_t)b * S_LEN + s) * F_DIM
                                        + threadIdx.x * 4);
    *(ushort4*)(xc + ((size_t)b * S_LEN + c) * F_DIM + threadIdx.x * 4) = v;
}

// ---------------- core 128x128 B^T GEMM tile (m97 structure) ----------------
// 256 threads = 4 waves in 2x2, each wave 64x64 via 4x4 mfma_f32_16x16x32_bf16.
// NOTE: __shared__ here is per-INSTANTIATION and summed across a kernel's calls.
template<class Epi>
__device__ __forceinline__ void gemm_tile_128(
    const u16* __restrict__ A, int lda,
    const u16* __restrict__ Bt, int ldb,
    int m0, int n0, int K, float alpha, Epi epi)
{
    __shared__ u16 la[128 * 32];
    __shared__ u16 lb[128 * 32];

    const int tid  = threadIdx.x;
    const int lane = tid & 63;
    const int wave = tid >> 6;
    const int wm = (wave & 1) * 64;
    const int wn = (wave >> 1) * 64;

    f32x4 acc[4][4];
#pragma unroll
    for (int mt = 0; mt < 4; mt++)
#pragma unroll
        for (int nt = 0; nt < 4; nt++)
            acc[mt][nt] = f32x4{0.f, 0.f, 0.f, 0.f};

    const int mrow = wm + (lane & 15);
    const int nrow = wn + (lane & 15);
    const int koff = (lane >> 4) * 8;

    const int cb0 = wave * 64;
    const int cb1 = wave * 64 + 256;
    const int lrow = lane >> 2;
    const int lcol = (lane & 3) * 8;
    const u16* pa0 = A  + (size_t)(m0 + (cb0 >> 2) + lrow) * lda + lcol;
    const u16* pa1 = A  + (size_t)(m0 + (cb1 >> 2) + lrow) * lda + lcol;
    const u16* pb0 = Bt + (size_t)(n0 + (cb0 >> 2) + lrow) * ldb + lcol;
    const u16* pb1 = Bt + (size_t)(n0 + (cb1 >> 2) + lrow) * ldb + lcol;
    u16* qa0 = la + cb0 * 8;
    u16* qa1 = la + cb1 * 8;
    u16* qb0 = lb + cb0 * 8;
    u16* qb1 = lb + cb1 * 8;

    for (int kk = 0; kk < K; kk += 32) {
        __syncthreads();
        gload_lds16(pa0 + kk, qa0);
        gload_lds16(pa1 + kk, qa1);
        gload_lds16(pb0 + kk, qb0);
        gload_lds16(pb1 + kk, qb1);
        __syncthreads();

        bf16x8 fa[4], fb[4];
#pragma unroll
        for (int t = 0; t < 4; t++) {
            fa[t] = *(const bf16x8*)(la + (mrow + t * 16) * 32 + koff);
            fb[t] = *(const bf16x8*)(lb + (nrow + t * 16) * 32 + koff);
        }
#pragma unroll
        for (int mt = 0; mt < 4; mt++)
#pragma unroll
            for (int nt = 0; nt < 4; nt++)
                acc[mt][nt] = __builtin_amdgcn_mfma_f32_16x16x32_bf16(
                    fa[mt], fb[nt], acc[mt][nt], 0, 0, 0);
    }

    // C/D layout col=lane&15, row=(lane>>4)*4+reg  [verified m89/m91]
    const int col   = lane & 15;
    const int rquad = (lane >> 4) * 4;
#pragma unroll
    for (int mt = 0; mt < 4; mt++)
#pragma unroll
        for (int nt = 0; nt < 4; nt++) {
            const int n = n0 + wn + nt * 16 + col;
#pragma unroll
            for (int r = 0; r < 4; r++) {
                const int m = m0 + wm + mt * 16 + rquad + r;
                epi(m, n, acc[mt][nt][r] * alpha);
            }
        }
}

// ---------------- Q projection (128^2 tile, full rows) ----------------
// XCD swizzle: xcd = bx&7 owns m-tiles [16*xcd,16*xcd+16).
__global__ __launch_bounds__(256) void k_q(const u16* __restrict__ xb,
                                           const u16* __restrict__ Wb,
                                           const float* __restrict__ bq,
                                           u16* __restrict__ q) {
    const int bx = blockIdx.x;
    const int xcd = bx & 7;
    const int idx = bx >> 3;
    const int m0 = (xcd * 16 + (idx >> 3)) * 128;
    const int n0 = (idx & 7) * 128;
    gemm_tile_128(xb, F_DIM, Wb, F_DIM, m0, n0, F_DIM, 1.0f,
        [&](int m, int n, float v) {
            q[(size_t)m * F_DIM + n] = f32_to_bf16_rne(v + bq[n]);
        });
}

// ---------------- K/V projection (128^2 tile, compacted rows) ----------------
// y=0 -> kc plain store; y=1 -> vTc[b][n][c] transposed, (c<cnt)?h:0 fills tail.
// Early-exit m-tiles beyond cnt. XCD swizzle as k_q. Two instantiations (32KB).
__global__ __launch_bounds__(256) void k_kv(const u16* __restrict__ xc,
                                            const u16* __restrict__ Wb,
                                            const float* __restrict__ bk,
                                            const float* __restrict__ bv,
                                            const int* __restrict__ kneed,
                                            u16* __restrict__ kc,
                                            u16* __restrict__ vTc) {
    const int which = blockIdx.y;              // 0=k, 1=v (block-uniform)
    const int bx = blockIdx.x;
    const int xcd = bx & 7;
    const int idx = bx >> 3;
    const int m0 = (xcd * 16 + (idx >> 3)) * 128;
    const int n0 = (idx & 7) * 128;
    const int b  = m0 >> 11;
    const int cnt = kneed[b * 16 + 15];
    if ((m0 & 2047) >= cnt) return;            // compacted rows only
    const float* bias = which ? bv : bk;
    const u16* W = Wb + (size_t)(which + 1) * F_DIM * F_DIM;
    if (which == 0) {
        gemm_tile_128(xc, F_DIM, W, F_DIM, m0, n0, F_DIM, 1.0f,
            [&](int m, int n, float v) {
                kc[(size_t)m * F_DIM + n] = f32_to_bf16_rne(v + bias[n]);
            });
    } else {
        gemm_tile_128(xc, F_DIM, W, F_DIM, m0, n0, F_DIM, 1.0f,
            [&](int m, int n, float v) {
                const int c = m & 2047;
                vTc[((size_t)b * F_DIM + n) * S_LEN + c] =
                    (c < cnt) ? f32_to_bf16_rne(v + bias[n]) : (u16)0;
            });
    }
}

// ---------------- scores -> P'c = exp(s-16), compacted cols + fused row sums ------
// 1D grid 1088; batch = bx&7 -> XCD. Early-exit tiles beyond kneed(it).
// Mask via sIdx[c] <= m (sentinel covers pad+gap -> writes 0).
__global__ __launch_bounds__(256) void k_scores(const u16* __restrict__ q,
                                                const u16* __restrict__ kc,
                                                const int* __restrict__ sIdx,
                                                const int* __restrict__ kneed,
                                                u16* __restrict__ Pp,
                                                float* __restrict__ lsum) {
    const int b = blockIdx.x & 7;
    const int t = blockIdx.x >> 3;        // 0..135 triangular index
    int it = 0, base = 0;
    while (base + it + 1 <= t) { base += it + 1; it++; }
    const int jt = t - base;
    if (jt * 128 >= kneed[b * 16 + it]) return;
    const int* sIb = sIdx + b * S_LEN;
    u16* Pb = Pp + (size_t)b * S_LEN * S_LEN;

    float rs[16];
#pragma unroll
    for (int i = 0; i < 16; i++) rs[i] = 0.f;

    gemm_tile_128(q + (size_t)b * S_LEN * F_DIM, F_DIM,
                  kc + (size_t)b * S_LEN * F_DIM, F_DIM,
                  it * 128, jt * 128, F_DIM, 0.03125f,
        [&](int m, int n, float v) {
            u16 o = 0;
            if (sIb[n] <= m)
                o = f32_to_bf16_rne(__expf(v - 16.0f));
            Pb[(size_t)m * S_LEN + n] = o;
            const int i = m & 63;
            rs[((i >> 4) << 2) | (i & 3)] += bf16_to_f32(o);
        });

    const int lane  = threadIdx.x & 63;
    const int wave  = threadIdx.x >> 6;
    const int wm    = (wave & 1) * 64;
    const int rquad = (lane >> 4) * 4;
    float* lb = lsum + b * S_LEN + it * 128 + wm;
#pragma unroll
    for (int i = 0; i < 16; i++) {        // i = mt*4 + r
        float s = rs[i];
        s += __shfl_xor(s, 1);
        s += __shfl_xor(s, 2);
        s += __shfl_xor(s, 4);
        s += __shfl_xor(s, 8);            // uniform across the 16 col-lanes
        if ((lane & 15) == 0)
            atomicAdd(&lb[((i >> 2) << 4) + rquad + (i & 3)], s);
    }
}

// ---------------- PV: out = (P'c @ Vc) / l, Keff = ceil128(kneed(it)) ---------
// 1D grid 1024; batch = bx&7 -> XCD. Heavy/light interleave on it.
__global__ __launch_bounds__(256) void k_pv(const u16* __restrict__ Pp,
                                            const u16* __restrict__ vTc,
                                            const float* __restrict__ lsum,
                                            const int* __restrict__ kneed,
                                            float* __restrict__ out) {
    const int b = blockIdx.x & 7;
    const int rest = blockIdx.x >> 3;
    const int j = rest >> 3;
    const int nt = rest & 7;
    const int it = (j & 1) ? (j >> 1) : (15 - (j >> 1));
    const int Keff = (kneed[b * 16 + it] + 127) & ~127;
    const float* ls = lsum + b * S_LEN;
    float* ob = out + (size_t)b * S_LEN * F_DIM;

    const int lane  = threadIdx.x & 63;
    const int wave  = threadIdx.x >> 6;
    const int wm    = (wave & 1) * 64;
    const int rquad = (lane >> 4) * 4;
    const int mb    = it * 128 + wm;
    float myinv[16];
#pragma unroll
    for (int i = 0; i < 16; i++)          // i = mt*4 + r
        myinv[i] = 1.0f / ls[mb + ((i >> 2) << 4) + rquad + (i & 3)];

    gemm_tile_128(Pp + (size_t)b * S_LEN * S_LEN, S_LEN,
                  vTc + (size_t)b * F_DIM * S_LEN, S_LEN,
                  it * 128, nt * 128, Keff, 1.0f,
        [&](int m, int n, float v) {
            const int i = m & 63;
            ob[(size_t)m * F_DIM + n] = v * myinv[((i >> 4) << 2) | (i & 3)];
        });
}

extern "C" void kernel_launch(void* const* d_in, const int* in_sizes, int n_in,
                              void* d_out, int out_size, void* d_ws, size_t ws_size,
                              hipStream_t stream) {
    const float* x  = (const float*)d_in[0];
    // d_in[1] = attn_mask (causal tril) — structure hard-coded
    const int* pad  = (const int*)d_in[2];
    const float* Wq = (const float*)d_in[3];
    const float* bq = (const float*)d_in[4];
    const float* Wk = (const float*)d_in[5];
    const float* bk = (const float*)d_in[6];
    const float* Wv = (const float*)d_in[7];
    const float* bv = (const float*)d_in[8];
    float* out = (float*)d_out;

    char* ws = (char*)d_ws;
    // layout:
    //   [0,32M)    q    bf16 [8][2048][1024]
    //   [32,64M)   kc   bf16 [8][2048][1024]  (compacted rows; >=cnt garbage/masked)
    //   [64,96M)   vTc  bf16 [8][1024][2048]  (compacted cols; tail zeroed by epi)
    //   [96,160M)  P'c  bf16 [8][2048][2048]  -- first 32M double as xc before scores
    //   [160,192M) xb   bf16 [16384][1024]
    //   [192,198M) Wb   bf16 [3][1024][1024]
    //   [200M)     lsum f32 [16384]
    //   [202M)     sIdx i32 [8][2048]
    //   [203M)     kneed i32 [8][16]
    u16* q    = (u16*)(ws);
    u16* kc   = (u16*)(ws + 32ull * 1024 * 1024);
    u16* vTc  = (u16*)(ws + 64ull * 1024 * 1024);
    u16* Pp   = (u16*)(ws + 96ull * 1024 * 1024);
    u16* xc   = (u16*)(ws + 96ull * 1024 * 1024);   // aliases Pp[0:32M), dead by scores
    u16* xb   = (u16*)(ws + 160ull * 1024 * 1024);
    u16* Wb   = (u16*)(ws + 192ull * 1024 * 1024);
    float* il = (float*)(ws + 200ull * 1024 * 1024);
    int* sIdx = (int*)(ws + 202ull * 1024 * 1024);
    int* kneed= (int*)(ws + 203ull * 1024 * 1024);

    const int BSF = BS_TOT * F_DIM;      // 16,777,216
    const int FF = F_DIM * F_DIM;        // 1,048,576

    hipMemsetAsync(il, 0, BS_TOT * sizeof(float), stream);

    cvt_f32_bf16<<<BSF / 1024, 256, 0, stream>>>(x, xb, BSF);
    cvt_w3<<<dim3(FF / 1024, 3), 256, 0, stream>>>(Wq, Wk, Wv, Wb);
    k_scan<<<NBATCH, 256, 0, stream>>>(pad, sIdx, kneed);
    k_gather<<<BS_TOT, 256, 0, stream>>>(xb, sIdx, kneed, xc);

    k_q<<<1024, 256, 0, stream>>>(xb, Wb, bq, q);
    k_kv<<<dim3(1024, 2), 256, 0, stream>>>(xc, Wb, bk, bv, kneed, kc, vTc);

    k_scores<<<1088, 256, 0, stream>>>(q, kc, sIdx, kneed, Pp, il);

    k_pv<<<1024, 256, 0, stream>>>(Pp, vTc, il, kneed, out);
}

// Round 11
// 330.194 us; speedup vs baseline: 1.1364x; 1.0578x over previous
//
#include <hip/hip_runtime.h>
#include <hip/hip_bf16.h>
#include <stdint.h>

// Problem: B=8, S=2048, F=1024 single-head causal self-attention.
// R4: P'=exp(s-16) folded into scores epilogue. R5-R7: 8-phase abandoned.
// R12: input-side pad compaction -> 335us (best). R13: 256x128 tile falsified.
// R14: k_q/k_kv split (measurement round): k_kv 75-78us, k_q/scores/pv all <75;
//   split cost ~14us (137 vs 120 merged) and ~45us total sits in dispatch gaps
//   across 9 dispatches.
// R15: consolidation. (1) k_q+k_kv re-merged into R12's k_qkv verbatim (proven
//   119.8us). (2) cvt_f32_bf16+cvt_w3 -> one k_cvt. (3) lsum zeroing folded
//   into k_scan; memset deleted. 9 dispatches -> 6. No new structure.

#define S_LEN 2048
#define F_DIM 1024
#define NBATCH 8
#define BS_TOT (NBATCH * S_LEN)   // 16384 rows

typedef __attribute__((ext_vector_type(8))) short bf16x8;
typedef __attribute__((ext_vector_type(4))) float f32x4;
typedef unsigned short u16;

__device__ __forceinline__ u16 f32_to_bf16_rne(float f) {
    union { float f; uint32_t u; } v; v.f = f;
    uint32_t u = v.u;
    u += 0x7FFFu + ((u >> 16) & 1u);
    return (u16)(u >> 16);
}
__device__ __forceinline__ float bf16_to_f32(u16 h) {
    union { uint32_t u; float f; } v; v.u = ((uint32_t)h) << 16;
    return v.f;
}

// async global->LDS, 16B per lane per instruction (global_load_lds_dwordx4)
__device__ __forceinline__ void gload_lds16(const u16* g, u16* l) {
    __builtin_amdgcn_global_load_lds(
        (const __attribute__((address_space(1))) void*)g,
        (__attribute__((address_space(3))) void*)l,
        16, 0, 0);
}

// ---------------- fused fp32 -> bf16 convert (x + Wq/Wk/Wv) ----------------
// blocks [0,16384): x -> xb.  blocks [16384,19456): W[which] -> Wb[which].
__global__ __launch_bounds__(256) void k_cvt(const float* __restrict__ x,
                                             const float* __restrict__ Wq,
                                             const float* __restrict__ Wk,
                                             const float* __restrict__ Wv,
                                             u16* __restrict__ xb,
                                             u16* __restrict__ Wb) {
    const int bx = blockIdx.x;
    const float* src;
    u16* dst;
    int i;
    if (bx < 16384) {
        i = bx * 1024 + threadIdx.x * 4;
        src = x; dst = xb;
    } else {
        const int rel = (bx - 16384) * 1024 + threadIdx.x * 4;
        const int which = rel >> 20;               // FF = 2^20
        i = rel & ((1 << 20) - 1);
        src = (which == 0) ? Wq : (which == 1) ? Wk : Wv;
        dst = Wb + (size_t)which * F_DIM * F_DIM;
    }
    float4 f = *(const float4*)(src + i);
    ushort4 o;
    o.x = f32_to_bf16_rne(f.x); o.y = f32_to_bf16_rne(f.y);
    o.z = f32_to_bf16_rne(f.z); o.w = f32_to_bf16_rne(f.w);
    *(ushort4*)(dst + i) = o;
}

// ---------------- pad prefix scan (one block per batch) + lsum zero ----------
// sIdx[b][c]  = original s for compacted c; sentinel S_LEN for c >= cnt
// kneed[b][it] = # valid keys with s <= (it+1)*128-1   (kneed[b][15] = cnt)
__global__ __launch_bounds__(256) void k_scan(const int* __restrict__ pad,
                                              int* __restrict__ sIdx,
                                              int* __restrict__ kneed,
                                              float* __restrict__ lsum) {
    const int b = blockIdx.x;
    const int tid = threadIdx.x;
    const int* p = pad + b * S_LEN;
    __shared__ int part[256];
    __shared__ int cnt_s;
    int v[8]; int sum = 0; const int s0 = tid * 8;
#pragma unroll
    for (int i = 0; i < 8; i++) { v[i] = p[s0 + i]; sum += v[i]; }
    part[tid] = sum;
    // zero this batch's lsum while the scan barrier settles
#pragma unroll
    for (int i = 0; i < 8; i++) lsum[b * S_LEN + tid * 8 + i] = 0.f;
    __syncthreads();
    if (tid == 0) {
        int acc = 0;
        for (int i = 0; i < 256; i++) { int t = part[i]; part[i] = acc; acc += t; }
        cnt_s = acc;
    }
    __syncthreads();
    int run = part[tid];
#pragma unroll
    for (int i = 0; i < 8; i++) {
        const int s = s0 + i;
        if (v[i]) sIdx[b * S_LEN + run] = s;
        run += v[i];
    }
    const int cnt = cnt_s;
    for (int c = cnt + tid; c < S_LEN; c += 256) sIdx[b * S_LEN + c] = S_LEN;
    if (tid < 16) {
        const int et = (tid + 1) * 16 - 1;
        kneed[b * 16 + tid] = (et == 255) ? cnt : part[et + 1];
    }
}

// ---------------- gather valid rows: xc[b][c][:] = xb[b][sIdx[c]][:] -------------
__global__ __launch_bounds__(256) void k_gather(const u16* __restrict__ xb,
                                                const int* __restrict__ sIdx,
                                                const int* __restrict__ kneed,
                                                u16* __restrict__ xc) {
    const int b = blockIdx.x >> 11, c = blockIdx.x & 2047;
    if (c >= kneed[b * 16 + 15]) return;
    const int s = sIdx[b * S_LEN + c];
    const ushort4 v = *(const ushort4*)(xb + ((size_t)b * S_LEN + s) * F_DIM
                                        + threadIdx.x * 4);
    *(ushort4*)(xc + ((size_t)b * S_LEN + c) * F_DIM + threadIdx.x * 4) = v;
}

// ---------------- core 128x128 B^T GEMM tile (m97 structure) ----------------
// 256 threads = 4 waves in 2x2, each wave 64x64 via 4x4 mfma_f32_16x16x32_bf16.
// NOTE: __shared__ here is per-INSTANTIATION and summed across a kernel's calls.
template<class Epi>
__device__ __forceinline__ void gemm_tile_128(
    const u16* __restrict__ A, int lda,
    const u16* __restrict__ Bt, int ldb,
    int m0, int n0, int K, float alpha, Epi epi)
{
    __shared__ u16 la[128 * 32];
    __shared__ u16 lb[128 * 32];

    const int tid  = threadIdx.x;
    const int lane = tid & 63;
    const int wave = tid >> 6;
    const int wm = (wave & 1) * 64;
    const int wn = (wave >> 1) * 64;

    f32x4 acc[4][4];
#pragma unroll
    for (int mt = 0; mt < 4; mt++)
#pragma unroll
        for (int nt = 0; nt < 4; nt++)
            acc[mt][nt] = f32x4{0.f, 0.f, 0.f, 0.f};

    const int mrow = wm + (lane & 15);
    const int nrow = wn + (lane & 15);
    const int koff = (lane >> 4) * 8;

    const int cb0 = wave * 64;
    const int cb1 = wave * 64 + 256;
    const int lrow = lane >> 2;
    const int lcol = (lane & 3) * 8;
    const u16* pa0 = A  + (size_t)(m0 + (cb0 >> 2) + lrow) * lda + lcol;
    const u16* pa1 = A  + (size_t)(m0 + (cb1 >> 2) + lrow) * lda + lcol;
    const u16* pb0 = Bt + (size_t)(n0 + (cb0 >> 2) + lrow) * ldb + lcol;
    const u16* pb1 = Bt + (size_t)(n0 + (cb1 >> 2) + lrow) * ldb + lcol;
    u16* qa0 = la + cb0 * 8;
    u16* qa1 = la + cb1 * 8;
    u16* qb0 = lb + cb0 * 8;
    u16* qb1 = lb + cb1 * 8;

    for (int kk = 0; kk < K; kk += 32) {
        __syncthreads();
        gload_lds16(pa0 + kk, qa0);
        gload_lds16(pa1 + kk, qa1);
        gload_lds16(pb0 + kk, qb0);
        gload_lds16(pb1 + kk, qb1);
        __syncthreads();

        bf16x8 fa[4], fb[4];
#pragma unroll
        for (int t = 0; t < 4; t++) {
            fa[t] = *(const bf16x8*)(la + (mrow + t * 16) * 32 + koff);
            fb[t] = *(const bf16x8*)(lb + (nrow + t * 16) * 32 + koff);
        }
#pragma unroll
        for (int mt = 0; mt < 4; mt++)
#pragma unroll
            for (int nt = 0; nt < 4; nt++)
                acc[mt][nt] = __builtin_amdgcn_mfma_f32_16x16x32_bf16(
                    fa[mt], fb[nt], acc[mt][nt], 0, 0, 0);
    }

    // C/D layout col=lane&15, row=(lane>>4)*4+reg  [verified m89/m91]
    const int col   = lane & 15;
    const int rquad = (lane >> 4) * 4;
#pragma unroll
    for (int mt = 0; mt < 4; mt++)
#pragma unroll
        for (int nt = 0; nt < 4; nt++) {
            const int n = n0 + wn + nt * 16 + col;
#pragma unroll
            for (int r = 0; r < 4; r++) {
                const int m = m0 + wm + mt * 16 + rquad + r;
                epi(m, n, acc[mt][nt][r] * alpha);
            }
        }
}

// ---------------- QKV projection (R12 form, proven 119.8us) ----------------
// y=0: q = xb.Wq (full). y=1: kc = xc.Wk (compacted rows, plain store, early-exit
// beyond cnt). y=2: vTc[b][n][c] = xc.Wv transposed store, (c<cnt)?h:0 zero-fills
// the tail. Two gemm instantiations (32KB LDS).
// XCD swizzle: xcd = bx&7 owns m-tiles [16*xcd,16*xcd+16).
__global__ __launch_bounds__(256) void k_qkv(const u16* __restrict__ xb,
                                             const u16* __restrict__ xc,
                                             const u16* __restrict__ Wb,
                                             const float* __restrict__ bq,
                                             const float* __restrict__ bk,
                                             const float* __restrict__ bv,
                                             const int* __restrict__ kneed,
                                             u16* __restrict__ q,
                                             u16* __restrict__ kc,
                                             u16* __restrict__ vTc) {
    const int which = blockIdx.y;
    const int bx = blockIdx.x;
    const int xcd = bx & 7;
    const int idx = bx >> 3;
    const int m0 = (xcd * 16 + (idx >> 3)) * 128;
    const int n0 = (idx & 7) * 128;
    const int b  = m0 >> 11;
    const int cnt = kneed[b * 16 + 15];
    if (which > 0 && (m0 & 2047) >= cnt) return;   // k/v: compacted rows only
    const float* bias = (which == 0) ? bq : (which == 1) ? bk : bv;
    const u16* W = Wb + (size_t)which * F_DIM * F_DIM;
    const u16* A = (which == 0) ? xb : xc;
    if (which < 2) {
        u16* o = (which == 0) ? q : kc;
        gemm_tile_128(A, F_DIM, W, F_DIM, m0, n0, F_DIM, 1.0f,
            [&](int m, int n, float v) {
                o[(size_t)m * F_DIM + n] = f32_to_bf16_rne(v + bias[n]);
            });
    } else {
        gemm_tile_128(A, F_DIM, W, F_DIM, m0, n0, F_DIM, 1.0f,
            [&](int m, int n, float v) {
                const int c = m & 2047;
                vTc[((size_t)b * F_DIM + n) * S_LEN + c] =
                    (c < cnt) ? f32_to_bf16_rne(v + bias[n]) : (u16)0;
            });
    }
}

// ---------------- scores -> P'c = exp(s-16), compacted cols + fused row sums ------
// 1D grid 1088; batch = bx&7 -> XCD. Early-exit tiles beyond kneed(it).
// Mask via sIdx[c] <= m (sentinel covers pad+gap -> writes 0).
__global__ __launch_bounds__(256) void k_scores(const u16* __restrict__ q,
                                                const u16* __restrict__ kc,
                                                const int* __restrict__ sIdx,
                                                const int* __restrict__ kneed,
                                                u16* __restrict__ Pp,
                                                float* __restrict__ lsum) {
    const int b = blockIdx.x & 7;
    const int t = blockIdx.x >> 3;        // 0..135 triangular index
    int it = 0, base = 0;
    while (base + it + 1 <= t) { base += it + 1; it++; }
    const int jt = t - base;
    if (jt * 128 >= kneed[b * 16 + it]) return;
    const int* sIb = sIdx + b * S_LEN;
    u16* Pb = Pp + (size_t)b * S_LEN * S_LEN;

    float rs[16];
#pragma unroll
    for (int i = 0; i < 16; i++) rs[i] = 0.f;

    gemm_tile_128(q + (size_t)b * S_LEN * F_DIM, F_DIM,
                  kc + (size_t)b * S_LEN * F_DIM, F_DIM,
                  it * 128, jt * 128, F_DIM, 0.03125f,
        [&](int m, int n, float v) {
            u16 o = 0;
            if (sIb[n] <= m)
                o = f32_to_bf16_rne(__expf(v - 16.0f));
            Pb[(size_t)m * S_LEN + n] = o;
            const int i = m & 63;
            rs[((i >> 4) << 2) | (i & 3)] += bf16_to_f32(o);
        });

    const int lane  = threadIdx.x & 63;
    const int wave  = threadIdx.x >> 6;
    const int wm    = (wave & 1) * 64;
    const int rquad = (lane >> 4) * 4;
    float* lb = lsum + b * S_LEN + it * 128 + wm;
#pragma unroll
    for (int i = 0; i < 16; i++) {        // i = mt*4 + r
        float s = rs[i];
        s += __shfl_xor(s, 1);
        s += __shfl_xor(s, 2);
        s += __shfl_xor(s, 4);
        s += __shfl_xor(s, 8);            // uniform across the 16 col-lanes
        if ((lane & 15) == 0)
            atomicAdd(&lb[((i >> 2) << 4) + rquad + (i & 3)], s);
    }
}

// ---------------- PV: out = (P'c @ Vc) / l, Keff = ceil128(kneed(it)) ---------
// 1D grid 1024; batch = bx&7 -> XCD. Heavy/light interleave on it.
__global__ __launch_bounds__(256) void k_pv(const u16* __restrict__ Pp,
                                            const u16* __restrict__ vTc,
                                            const float* __restrict__ lsum,
                                            const int* __restrict__ kneed,
                                            float* __restrict__ out) {
    const int b = blockIdx.x & 7;
    const int rest = blockIdx.x >> 3;
    const int j = rest >> 3;
    const int nt = rest & 7;
    const int it = (j & 1) ? (j >> 1) : (15 - (j >> 1));
    const int Keff = (kneed[b * 16 + it] + 127) & ~127;
    const float* ls = lsum + b * S_LEN;
    float* ob = out + (size_t)b * S_LEN * F_DIM;

    const int lane  = threadIdx.x & 63;
    const int wave  = threadIdx.x >> 6;
    const int wm    = (wave & 1) * 64;
    const int rquad = (lane >> 4) * 4;
    const int mb    = it * 128 + wm;
    float myinv[16];
#pragma unroll
    for (int i = 0; i < 16; i++)          // i = mt*4 + r
        myinv[i] = 1.0f / ls[mb + ((i >> 2) << 4) + rquad + (i & 3)];

    gemm_tile_128(Pp + (size_t)b * S_LEN * S_LEN, S_LEN,
                  vTc + (size_t)b * F_DIM * S_LEN, S_LEN,
                  it * 128, nt * 128, Keff, 1.0f,
        [&](int m, int n, float v) {
            const int i = m & 63;
            ob[(size_t)m * F_DIM + n] = v * myinv[((i >> 4) << 2) | (i & 3)];
        });
}

extern "C" void kernel_launch(void* const* d_in, const int* in_sizes, int n_in,
                              void* d_out, int out_size, void* d_ws, size_t ws_size,
                              hipStream_t stream) {
    const float* x  = (const float*)d_in[0];
    // d_in[1] = attn_mask (causal tril) — structure hard-coded
    const int* pad  = (const int*)d_in[2];
    const float* Wq = (const float*)d_in[3];
    const float* bq = (const float*)d_in[4];
    const float* Wk = (const float*)d_in[5];
    const float* bk = (const float*)d_in[6];
    const float* Wv = (const float*)d_in[7];
    const float* bv = (const float*)d_in[8];
    float* out = (float*)d_out;

    char* ws = (char*)d_ws;
    // layout:
    //   [0,32M)    q    bf16 [8][2048][1024]
    //   [32,64M)   kc   bf16 [8][2048][1024]  (compacted rows; >=cnt garbage/masked)
    //   [64,96M)   vTc  bf16 [8][1024][2048]  (compacted cols; tail zeroed by epi)
    //   [96,160M)  P'c  bf16 [8][2048][2048]  -- first 32M double as xc before scores
    //   [160,192M) xb   bf16 [16384][1024]
    //   [192,198M) Wb   bf16 [3][1024][1024]
    //   [200M)     lsum f32 [16384]
    //   [202M)     sIdx i32 [8][2048]
    //   [203M)     kneed i32 [8][16]
    u16* q    = (u16*)(ws);
    u16* kc   = (u16*)(ws + 32ull * 1024 * 1024);
    u16* vTc  = (u16*)(ws + 64ull * 1024 * 1024);
    u16* Pp   = (u16*)(ws + 96ull * 1024 * 1024);
    u16* xc   = (u16*)(ws + 96ull * 1024 * 1024);   // aliases Pp[0:32M), dead by scores
    u16* xb   = (u16*)(ws + 160ull * 1024 * 1024);
    u16* Wb   = (u16*)(ws + 192ull * 1024 * 1024);
    float* il = (float*)(ws + 200ull * 1024 * 1024);
    int* sIdx = (int*)(ws + 202ull * 1024 * 1024);
    int* kneed= (int*)(ws + 203ull * 1024 * 1024);

    k_cvt<<<19456, 256, 0, stream>>>(x, Wq, Wk, Wv, xb, Wb);
    k_scan<<<NBATCH, 256, 0, stream>>>(pad, sIdx, kneed, il);
    k_gather<<<BS_TOT, 256, 0, stream>>>(xb, sIdx, kneed, xc);

    k_qkv<<<dim3(1024, 3), 256, 0, stream>>>(xb, xc, Wb, bq, bk, bv, kneed,
                                             q, kc, vTc);

    k_scores<<<1088, 256, 0, stream>>>(q, kc, sIdx, kneed, Pp, il);

    k_pv<<<1024, 256, 0, stream>>>(Pp, vTc, il, kneed, out);
}